// Round 1
// baseline (46.586 us; speedup 1.0000x reference)
//
#include <hip/hip_runtime.h>
#include <hip/hip_fp16.h>

#define N 8192
#define D 128
#define MARGIN 0.3f
#define NCHUNK 8     // j-chunks (blocks along j)
#define JTILES 8     // 128-wide j-tiles per chunk (1024/128)

typedef __fp16 half_t;
typedef __attribute__((ext_vector_type(8))) __fp16 half8;
typedef __attribute__((ext_vector_type(4))) float f32x4;

// ---------------- prep: fp32 -> fp16, exact fp32 norms, zero accumulators ----
__global__ void triplet_prep(const float* __restrict__ x,
                             half_t* __restrict__ xh,
                             float* __restrict__ norms,
                             float* __restrict__ gacc) {
    const int gt = blockIdx.x * 256 + threadIdx.x;
    if (gt < 2) gacc[gt] = 0.f;
    const int row  = gt >> 6;      // one wave per row
    const int lane = gt & 63;
    const float* rp = x + (size_t)row * D;
    float a0 = rp[lane], a1 = rp[lane + 64];
    xh[(size_t)row * D + lane]      = (half_t)a0;
    xh[(size_t)row * D + lane + 64] = (half_t)a1;
    float s = fmaf(a0, a0, a1 * a1);
#pragma unroll
    for (int o = 32; o > 0; o >>= 1) s += __shfl_xor(s, o);
    if (lane == 0) norms[row] = s;
}

// ---------------- main: fused fp16-MFMA Gram + masked row max/min ------------
// grid: 64 row-strips x 8 j-chunks = 512 blocks (2/CU). block: 256 thr = 4 waves (2x2).
// Each wave owns a 64x64 quadrant of the 128x128 C tile: acc[4][4] frags of 16x16x32.
__launch_bounds__(256, 2)
__global__ void triplet_main(const half_t* __restrict__ xh,
                             const float* __restrict__ norms,
                             const int* __restrict__ labels,
                             float* __restrict__ ppos,
                             float* __restrict__ pneg) {
    // LDS: [row][16 slots of 8 halves], phys slot = logical slot ^ (row&7)  (bank swizzle)
    __shared__ __align__(16) half_t Ah[128 * 128];
    __shared__ __align__(16) half_t Bh[128 * 128];

    const int bx    = blockIdx.x;
    const int strip = bx >> 3;
    const int chunk = bx & 7;
    const int tid   = threadIdx.x;
    const int lane  = tid & 63;
    const int w     = tid >> 6;
    const int wr    = w >> 1;
    const int wc    = w & 1;
    const int lrow  = lane >> 4;   // 0..3  (k-group / C row-group)
    const int lcol  = lane & 15;   // 0..15 (A row / B col / C col)

    const int irow0 = strip * 128;

    // ---- stage A panel once (swizzled) ----
#pragma unroll
    for (int it = 0; it < 8; ++it) {
        int f = it * 256 + tid;          // flat 16B slot: row = f>>4, phys slot = f&15
        int row = f >> 4, sp = f & 15;
        int sl = sp ^ (row & 7);
        *(uint4*)(Ah + f * 8) = *(const uint4*)(xh + (size_t)(irow0 + row) * D + sl * 8);
    }

    // per-lane constant LDS offsets; row&7 == lcol&7 for all frags (wr*64, f*16 ≡ 0 mod 8)
    int physk[4];
#pragma unroll
    for (int ks = 0; ks < 4; ++ks) physk[ks] = ((ks * 4 + lrow) ^ (lcol & 7)) * 8;
    int rowA[4], rowB[4];
#pragma unroll
    for (int f4 = 0; f4 < 4; ++f4) {
        rowA[f4] = (wr * 64 + f4 * 16 + lcol) * D;
        rowB[f4] = (wc * 64 + f4 * 16 + lcol) * D;
    }

    // labels of my 16 owned C-rows (fixed for whole kernel)
    const int ibase = irow0 + wr * 64 + lrow * 4;
    int li[16];
#pragma unroll
    for (int fi = 0; fi < 4; ++fi)
#pragma unroll
        for (int rg = 0; rg < 4; ++rg)
            li[fi * 4 + rg] = labels[ibase + fi * 16 + rg];

    float mpos[16], mneg[16];
#pragma unroll
    for (int r = 0; r < 16; ++r) { mpos[r] = -1e38f; mneg[r] = 1e38f; }

    for (int jt = 0; jt < JTILES; ++jt) {
        const int jbase = chunk * 1024 + jt * 128;
        __syncthreads();                      // protect Bh readers of prev tile
#pragma unroll
        for (int it = 0; it < 8; ++it) {
            int f = it * 256 + tid;
            int row = f >> 4, sp = f & 15;
            int sl = sp ^ (row & 7);
            *(uint4*)(Bh + f * 8) = *(const uint4*)(xh + (size_t)(jbase + row) * D + sl * 8);
        }
        __syncthreads();

        int lj[4]; float njv[4];
#pragma unroll
        for (int fj = 0; fj < 4; ++fj) {
            int j = jbase + wc * 64 + fj * 16 + lcol;
            lj[fj]  = labels[j];
            njv[fj] = norms[j];
        }

        f32x4 acc[4][4];
#pragma unroll
        for (int fi = 0; fi < 4; ++fi)
#pragma unroll
            for (int fj = 0; fj < 4; ++fj)
                acc[fi][fj] = (f32x4){0.f, 0.f, 0.f, 0.f};

#pragma unroll
        for (int ks = 0; ks < 4; ++ks) {
            half8 av[4], bv[4];
#pragma unroll
            for (int fi = 0; fi < 4; ++fi)
                av[fi] = *(const half8*)(Ah + rowA[fi] + physk[ks]);
#pragma unroll
            for (int fj = 0; fj < 4; ++fj)
                bv[fj] = *(const half8*)(Bh + rowB[fj] + physk[ks]);
#pragma unroll
            for (int fi = 0; fi < 4; ++fi)
#pragma unroll
                for (int fj = 0; fj < 4; ++fj)
                    acc[fi][fj] = __builtin_amdgcn_mfma_f32_16x16x32_f16(
                        av[fi], bv[fj], acc[fi][fj], 0, 0, 0);
        }

        // epilogue: cand = n_j - 2 g_ij ; masked running max/min per owned row
        const bool hasdiag = (jbase == irow0);
        const int jcolbase = jbase + wc * 64 + lcol;
#pragma unroll
        for (int fi = 0; fi < 4; ++fi) {
#pragma unroll
            for (int fj = 0; fj < 4; ++fj) {
#pragma unroll
                for (int rg = 0; rg < 4; ++rg) {
                    float cand = fmaf(-2.f, acc[fi][fj][rg], njv[fj]);
                    int r = fi * 4 + rg;
                    bool same = (li[r] == lj[fj]);
                    bool pos = same;
                    if (hasdiag) {
                        int ig = ibase + fi * 16 + rg;
                        int jg = jcolbase + fj * 16;
                        pos = same && (ig != jg);
                    }
                    if (pos)   mpos[r] = fmaxf(mpos[r], cand);
                    if (!same) mneg[r] = fminf(mneg[r], cand);
                }
            }
        }
    }

    // reduce across the 16 col-lanes of each quarter-wave (C cols live on lcol)
#pragma unroll
    for (int o = 1; o < 16; o <<= 1) {
#pragma unroll
        for (int r = 0; r < 16; ++r) {
            mpos[r] = fmaxf(mpos[r], __shfl_xor(mpos[r], o));
            mneg[r] = fminf(mneg[r], __shfl_xor(mneg[r], o));
        }
    }
    if (lcol == 0) {
        const int slot = chunk * 2 + wc;   // 16 partial slots per row
#pragma unroll
        for (int fi = 0; fi < 4; ++fi)
#pragma unroll
            for (int rg = 0; rg < 4; ++rg) {
                int rgrow = ibase + fi * 16 + rg;
                ppos[(size_t)rgrow * 16 + slot] = mpos[fi * 4 + rg];
                pneg[(size_t)rgrow * 16 + slot] = mneg[fi * 4 + rg];
            }
    }
}

// ---------------- finalize rows: sqrt/relu/valid + global sum/count ----------
__global__ void triplet_reduce(const float* __restrict__ ppos,
                               const float* __restrict__ pneg,
                               const float* __restrict__ norms,
                               float* __restrict__ gacc) {
    __shared__ float ss[256];
    __shared__ float sc[256];
    const int tid = threadIdx.x;
    const int r   = blockIdx.x * 256 + tid;
    float mp = -1e38f, mn = 1e38f;
    const f32x4* pp = (const f32x4*)(ppos + (size_t)r * 16);
    const f32x4* pn = (const f32x4*)(pneg + (size_t)r * 16);
#pragma unroll
    for (int s4 = 0; s4 < 4; ++s4) {
        f32x4 a = pp[s4], b = pn[s4];
#pragma unroll
        for (int e = 0; e < 4; ++e) { mp = fmaxf(mp, a[e]); mn = fminf(mn, b[e]); }
    }
    float ni = norms[r];
    bool valid = (mp > -1e37f) && (mn < 1e37f);
    float hp = sqrtf(fmaxf(ni + mp, 0.f));
    float hn = sqrtf(fmaxf(ni + mn, 0.f));
    float pr = fmaxf(hp - hn + MARGIN, 0.f);
    ss[tid] = valid ? pr : 0.f;
    sc[tid] = valid ? 1.f : 0.f;
    __syncthreads();
    for (int o = 128; o > 0; o >>= 1) {
        if (tid < o) { ss[tid] += ss[tid + o]; sc[tid] += sc[tid + o]; }
        __syncthreads();
    }
    if (tid == 0) { atomicAdd(&gacc[0], ss[0]); atomicAdd(&gacc[1], sc[0]); }
}

__global__ void triplet_final(const float* __restrict__ gacc, float* __restrict__ out) {
    out[0] = (gacc[1] > 0.f) ? (gacc[0] / gacc[1]) : 0.f;
}

// -----------------------------------------------------------------------------
extern "C" void kernel_launch(void* const* d_in, const int* in_sizes, int n_in,
                              void* d_out, int out_size, void* d_ws, size_t ws_size,
                              hipStream_t stream) {
    const float* x      = (const float*)d_in[0];
    const int*   labels = (const int*)d_in[1];
    float*       out    = (float*)d_out;

    // ws layout: xh (2 MiB) | norms (32 KiB) | ppos (512 KiB) | pneg (512 KiB) | gacc (8 B)
    char*   ws    = (char*)d_ws;
    half_t* xh    = (half_t*)ws;
    float*  norms = (float*)(ws + (size_t)N * D * sizeof(half_t));
    float*  ppos  = norms + N;
    float*  pneg  = ppos + (size_t)N * 16;
    float*  gacc  = pneg + (size_t)N * 16;

    triplet_prep  <<<N / 4,   256, 0, stream>>>(x, xh, norms, gacc);
    triplet_main  <<<512,     256, 0, stream>>>(xh, norms, labels, ppos, pneg);
    triplet_reduce<<<N / 256, 256, 0, stream>>>(ppos, pneg, norms, gacc);
    triplet_final <<<1,       1,   0, stream>>>(gacc, out);
}